// Round 2
// baseline (908.670 us; speedup 1.0000x reference)
//
#include <hip/hip_runtime.h>

#define N_NODES 100000
#define N_EDGES 1600000
#define D_IN 128
#define D_HID 64

#define BKT_SHIFT 8
#define BKT_NODES 256
#define NB 391              // ceil(N_NODES / 256) buckets
#define NBLK 392            // scatter blocks
#define SLOT 32             // slots per (bucket,block): Poisson(10.4), +6.7 sigma
#define SLOTS_PB (NBLK * SLOT)   // 12544 slots per bucket region
#define OVF_CAP 8192
#define EST 512             // escatter block size

#define AP 68               // acc row stride in floats (padded: 68*4=272B, 16B-aligned, breaks bank alias)

typedef __attribute__((ext_vector_type(8))) short bf16x8;
typedef __attribute__((ext_vector_type(4))) float f32x4;

__device__ __forceinline__ unsigned short f2b(float f) {
    union { float f; unsigned u; } c; c.f = f;
    unsigned r = (c.u + 0x7FFFu + ((c.u >> 16) & 1u)) >> 16;   // RNE
    return (unsigned short)r;
}
__device__ __forceinline__ float blo(unsigned u) { return __uint_as_float(u << 16); }
__device__ __forceinline__ float bhi(unsigned u) { return __uint_as_float(u & 0xffff0000u); }

// ========== prep: W1 -> bf16 transposed, zero deg[] and overflow counter ==========
__global__ __launch_bounds__(256) void k_prep(const float* __restrict__ W1,
                                              unsigned short* __restrict__ w1t,
                                              int* __restrict__ ovf_cnt,
                                              int* __restrict__ deg, int n) {
    int t = blockIdx.x * 256 + threadIdx.x;          // 392*256 = 100352 threads
    if (t == 0) ovf_cnt[0] = 0;
    if (t < D_IN * D_HID) {                          // 8192
        int k = t >> 6, f = t & 63;                  // W1 is [128][64]
        w1t[f * D_IN + k] = f2b(W1[t]);
    }
    if (t < n) deg[t] = 0;
}

// ========== one-pass partition into bucket-major fixed-slot regions + degree =======
// code = (src << 8) | (dst & 255); region pairs[bucket][block][SLOT]
__global__ __launch_bounds__(EST) void k_escatter(const int* __restrict__ src,
                                                  const int* __restrict__ dst,
                                                  int* __restrict__ pairs,
                                                  int* __restrict__ cnt_blk,
                                                  int* __restrict__ ovf_cnt,
                                                  int2* __restrict__ ovf,
                                                  int* __restrict__ deg, int E) {
    __shared__ int lcur[NB];
    int tid = threadIdx.x;
    for (int t = tid; t < NB; t += EST) lcur[t] = 0;
    __syncthreads();
    int chunk = (E + NBLK - 1) / NBLK;
    int beg = blockIdx.x * chunk;
    int end = min(beg + chunk, E);
    for (int e = beg + tid; e < end; e += EST) {
        int d = dst[e], s = src[e];
        atomicAdd(&deg[d], 1);                       // global degree (for dis in gemm1)
        int bk = d >> BKT_SHIFT;
        int slot = atomicAdd(&lcur[bk], 1);
        if (slot < SLOT)
            pairs[(bk * NBLK + blockIdx.x) * SLOT + slot] = (s << BKT_SHIFT) | (d & (BKT_NODES - 1));
        else {
            int o = atomicAdd(ovf_cnt, 1);
            if (o < OVF_CAP) ovf[o] = make_int2(s, d);
        }
    }
    __syncthreads();
    for (int t = tid; t < NB; t += EST)
        cnt_blk[t * NBLK + blockIdx.x] = min(lcur[t], SLOT);
}

// ========== layer 1 GEMM via bf16 MFMA; computes dis=rsqrt(deg+1), scales rows =====
#define LS 136
__global__ __launch_bounds__(256) void k_gemm1(const float* __restrict__ x,
                                               const uint4* __restrict__ w1t4,
                                               const int* __restrict__ deg,
                                               float* __restrict__ dis,
                                               unsigned short* __restrict__ h1s, int n) {
    __shared__ unsigned short xs[64 * LS];
    __shared__ unsigned short ws[64 * LS];
    __shared__ float disb[64];
    int tid = threadIdx.x;
    int node0 = blockIdx.x * 64;

    if (tid < 64) {
        int node = node0 + tid;
        float dv = 0.f;
        if (node < n) { dv = rsqrtf((float)deg[node] + 1.0f); dis[node] = dv; }
        disb[tid] = dv;
    }
#pragma unroll
    for (int it = 0; it < 4; ++it) {
        int e = tid + it * 256;
        int f = e >> 4, c = e & 15;
        *(uint4*)&ws[f * LS + c * 8] = w1t4[e];
    }
#pragma unroll
    for (int it = 0; it < 8; ++it) {
        int e4 = tid + it * 256;
        int node = e4 >> 5;
        int k = (e4 & 31) * 4;
        float4 v = make_float4(0.f, 0.f, 0.f, 0.f);
        if (node0 + node < n)
            v = ((const float4*)x)[((size_t)(node0 + node) * D_IN + k) >> 2];
        uint2 u;
        u.x = (unsigned)f2b(v.x) | ((unsigned)f2b(v.y) << 16);
        u.y = (unsigned)f2b(v.z) | ((unsigned)f2b(v.w) << 16);
        *(uint2*)&xs[node * LS + k] = u;
    }
    __syncthreads();

    int wv = tid >> 6;
    int lane = tid & 63;
    int m16 = lane & 15;
    int q = lane >> 4;

    bf16x8 afrag[4];
#pragma unroll
    for (int ks = 0; ks < 4; ++ks)
        afrag[ks] = *(const bf16x8*)&xs[(wv * 16 + m16) * LS + ks * 32 + q * 8];

    f32x4 acc[4];
#pragma unroll
    for (int ft = 0; ft < 4; ++ft) acc[ft] = (f32x4){0.f, 0.f, 0.f, 0.f};

#pragma unroll
    for (int ft = 0; ft < 4; ++ft)
#pragma unroll
        for (int ks = 0; ks < 4; ++ks) {
            bf16x8 bfrag = *(const bf16x8*)&ws[(ft * 16 + m16) * LS + ks * 32 + q * 8];
            acc[ft] = __builtin_amdgcn_mfma_f32_16x16x32_bf16(afrag[ks], bfrag, acc[ft], 0, 0, 0);
        }

#pragma unroll
    for (int r = 0; r < 4; ++r) {
        int node = node0 + wv * 16 + q * 4 + r;
        if (node < n) {
            float d = disb[wv * 16 + q * 4 + r];
#pragma unroll
            for (int ft = 0; ft < 4; ++ft)
                h1s[(size_t)node * D_HID + ft * 16 + m16] = f2b(acc[ft][r] * d);
        }
    }
}

// ========== edge-centric agg1: ds_add_f32 into LDS acc, fused bias+ReLU+dot(W2) ====
// One block per bucket (1024 thr, 16 waves). Codes read coalesced; no sort, no
// dependent src chain, no dummy loads. 8 lanes per edge (feature chunks).
__global__ __launch_bounds__(1024) void k_agg1(const int* __restrict__ pairs,
                                               const int* __restrict__ cnt_blk,
                                               const int* __restrict__ ovf_cnt,
                                               const int2* __restrict__ ovf,
                                               const float* __restrict__ dis,
                                               const uint4* __restrict__ h4,
                                               const float* __restrict__ b1,
                                               const float* __restrict__ W2,
                                               float* __restrict__ zd, int n) {
    __shared__ float acc[BKT_NODES * AP];    // 69,632 B
    __shared__ int segc[NBLK];
    int b = blockIdx.x;
    int tid = threadIdx.x;
    int node0 = b << BKT_SHIFT;

    for (int i = tid; i < NBLK; i += 1024) segc[i] = cnt_blk[b * NBLK + i];
    for (int i = tid; i < BKT_NODES * AP; i += 1024) acc[i] = 0.f;
    __syncthreads();

    const int* pb = pairs + (size_t)b * SLOTS_PB;
    int wv = tid >> 6;        // wave 0..15
    int lane = tid & 63;
    int g = lane >> 3;        // edge group 0..7
    int m8 = lane & 7;        // feature chunk (8 floats)

#define ADD8(uu, aptr) { atomicAdd((aptr) + 0, blo(uu.x)); atomicAdd((aptr) + 1, bhi(uu.x)); \
                         atomicAdd((aptr) + 2, blo(uu.y)); atomicAdd((aptr) + 3, bhi(uu.y)); \
                         atomicAdd((aptr) + 4, blo(uu.z)); atomicAdd((aptr) + 5, bhi(uu.z)); \
                         atomicAdd((aptr) + 6, blo(uu.w)); atomicAdd((aptr) + 7, bhi(uu.w)); }

    // segments strided across waves; ~10.4 valid of 32 slots -> ~1.3 inner iters
#pragma unroll 2
    for (int s = 0; s < (NBLK + 15) / 16; ++s) {
        int sg = (s << 4) + wv;
        if (sg < NBLK) {
            int c = segc[sg];
            const int* base = pb + sg * SLOT;
            for (int k = g; k < c; k += 8) {
                unsigned code = (unsigned)base[k];
                uint4 uu = h4[(code >> 8) * 8u + m8];
                float* a = acc + (code & 255u) * AP + m8 * 8;
                ADD8(uu, a);
            }
        }
    }
    int ocnt = min(ovf_cnt[0], OVF_CAP);
    for (int k2 = tid; k2 < ocnt; k2 += 1024) {
        int2 e = ovf[k2];
        if ((e.y >> BKT_SHIFT) == b) {
            float* arow = acc + (e.y & (BKT_NODES - 1)) * AP;
            for (int c8 = 0; c8 < 8; ++c8) {
                uint4 uu = h4[(unsigned)e.x * 8u + c8];
                ADD8(uu, (arow + c8 * 8));
            }
        }
    }
#undef ADD8
    __syncthreads();

    // epilogue: 128 lane-groups of 8 -> 256 nodes in 2 rounds
    int grp = tid >> 3;
    int f8 = tid & 7;
#pragma unroll
    for (int r = 0; r < 2; ++r) {
        int nl = r * 128 + grp;
        int node = node0 + nl;
        float v = 0.f, dd = 0.f;
        if (node < n) {
            dd = dis[node];
            uint4 uu = h4[(unsigned)node * 8u + f8];   // self term (already dis-scaled)
            const float* a = acc + nl * AP + f8 * 8;
            float s0 = a[0] + blo(uu.x), s1 = a[1] + bhi(uu.x);
            float s2 = a[2] + blo(uu.y), s3 = a[3] + bhi(uu.y);
            float s4 = a[4] + blo(uu.z), s5 = a[5] + bhi(uu.z);
            float s6 = a[6] + blo(uu.w), s7 = a[7] + bhi(uu.w);
            float4 ba = ((const float4*)b1)[f8 * 2], bb = ((const float4*)b1)[f8 * 2 + 1];
            float4 wa = ((const float4*)W2)[f8 * 2], wb = ((const float4*)W2)[f8 * 2 + 1];
            v = fmaxf(fmaf(dd, s0, ba.x), 0.f) * wa.x + fmaxf(fmaf(dd, s1, ba.y), 0.f) * wa.y
              + fmaxf(fmaf(dd, s2, ba.z), 0.f) * wa.z + fmaxf(fmaf(dd, s3, ba.w), 0.f) * wa.w
              + fmaxf(fmaf(dd, s4, bb.x), 0.f) * wb.x + fmaxf(fmaf(dd, s5, bb.y), 0.f) * wb.y
              + fmaxf(fmaf(dd, s6, bb.z), 0.f) * wb.z + fmaxf(fmaf(dd, s7, bb.w), 0.f) * wb.w;
        }
        v += __shfl_xor(v, 1); v += __shfl_xor(v, 2); v += __shfl_xor(v, 4);
        if (f8 == 0 && node < n) zd[node] = v * dd;
    }
}

// ========== edge-centric agg2 + fused padded output ==========
__global__ __launch_bounds__(256) void k_agg2(const int* __restrict__ pairs,
                                              const int* __restrict__ cnt_blk,
                                              const int* __restrict__ ovf_cnt,
                                              const int2* __restrict__ ovf,
                                              const float* __restrict__ dis,
                                              const float* __restrict__ zd,
                                              const float* __restrict__ b2,
                                              float* __restrict__ out, int n) {
    __shared__ float acc2[BKT_NODES];
    __shared__ float yv[BKT_NODES];
    __shared__ int segc[NBLK];
    int b = blockIdx.x, tid = threadIdx.x;
    int node0 = b << BKT_SHIFT;
    for (int i = tid; i < NBLK; i += 256) segc[i] = cnt_blk[b * NBLK + i];
    if (tid < BKT_NODES) acc2[tid] = 0.f;
    __syncthreads();
    const int* pb = pairs + (size_t)b * SLOTS_PB;
    for (int it = 0; it < SLOTS_PB / 256; ++it) {     // 49 iters
        int e = it * 256 + tid;
        if ((e & (SLOT - 1)) < segc[e >> 5]) {
            unsigned code = (unsigned)pb[e];
            float v = zd[code >> 8];                  // zd is 400KB, L2-resident
            atomicAdd(&acc2[code & 255u], v);
        }
    }
    int ocnt = min(ovf_cnt[0], OVF_CAP);
    for (int k = tid; k < ocnt; k += 256) {
        int2 e = ovf[k];
        if ((e.y >> BKT_SHIFT) == b) atomicAdd(&acc2[e.y & (BKT_NODES - 1)], zd[e.x]);
    }
    __syncthreads();
    if (tid < BKT_NODES) {
        int node = node0 + tid;
        if (node < n) yv[tid] = (acc2[tid] + zd[node]) * dis[node] + b2[0];
    }
    __syncthreads();
    float4* out4 = (float4*)out;
    for (int i = tid; i < BKT_NODES * 32; i += 256) {
        int nl = i >> 5, l = i & 31;
        int node = node0 + nl;
        if (node < n) {
            float4 v = make_float4(0.f, 0.f, 0.f, 0.f);
            if (l == 0) v.x = yv[nl];
            out4[(size_t)node * 32 + l] = v;
        }
    }
}

extern "C" void kernel_launch(void* const* d_in, const int* in_sizes, int n_in,
                              void* d_out, int out_size, void* d_ws, size_t ws_size,
                              hipStream_t stream) {
    const float* x  = (const float*)d_in[0];
    const int*   ei = (const int*)d_in[1];   // [2, E] int32
    const float* W1 = (const float*)d_in[2];
    const float* b1 = (const float*)d_in[3];
    const float* W2 = (const float*)d_in[4];
    const float* b2 = (const float*)d_in[5];
    float* out = (float*)d_out;

    const int n = N_NODES;
    const int E = N_EDGES;
    const int* src = ei;
    const int* dst = ei + E;

    // ws: pairs int[NB*NBLK*SLOT] (19.6MB) | cnt_blk int[NB*NBLK] (613KB) |
    //     deg int[n] | ovf_cnt[4] | ovf int2[OVF_CAP] | dis f[n] |
    //     h1s ushort[n*64] (12.8MB) | w1t ushort[8192] | zd f[n]
    int* pairs       = (int*)d_ws;
    int* cnt_blk     = pairs + (size_t)NB * NBLK * SLOT;
    int* deg         = cnt_blk + (size_t)NB * NBLK;
    int* ovf_cnt     = deg + n;
    int2* ovf        = (int2*)(ovf_cnt + 4);
    float* dis       = (float*)(ovf + OVF_CAP);
    unsigned short* h1s = (unsigned short*)(dis + n);
    unsigned short* w1t = h1s + (size_t)n * D_HID;
    float* zd        = (float*)(w1t + D_IN * D_HID);

    k_prep<<<392, 256, 0, stream>>>(W1, w1t, ovf_cnt, deg, n);
    k_escatter<<<NBLK, EST, 0, stream>>>(src, dst, pairs, cnt_blk, ovf_cnt, ovf, deg, E);
    k_gemm1<<<(n + 63) / 64, 256, 0, stream>>>(x, (const uint4*)w1t, deg, dis, h1s, n);
    k_agg1<<<NB, 1024, 0, stream>>>(pairs, cnt_blk, ovf_cnt, ovf, dis,
                                    (const uint4*)h1s, b1, W2, zd, n);
    k_agg2<<<NB, 256, 0, stream>>>(pairs, cnt_blk, ovf_cnt, ovf, dis, zd, b2, out, n);
}

// Round 3
// 206.083 us; speedup vs baseline: 4.4092x; 4.4092x over previous
//
#include <hip/hip_runtime.h>

#define N_NODES 100000
#define N_EDGES 1600000
#define D_IN 128
#define D_HID 64

#define BKT_SHIFT 8
#define BKT_NODES 256
#define NB 391          // ceil(N_NODES / 256) buckets
#define NBLK 392        // scatter blocks
#define SLOT 32         // slots per (bucket,block): Poisson(10.4), +6.7 sigma
#define SEG4 (SLOT / 4) // uint4s per segment
#define REG4 (NBLK * SEG4)   // uint4s per bucket region = 3136
#define SLOTS_PB (NBLK * SLOT)
#define BKT_CAP 5120    // per-bucket capacity in srcs_sorted (mean 4092)
#define OVF_CAP 8192

#define EST 1024        // escatter block size
#define BST 1024        // bsort block size

typedef __attribute__((ext_vector_type(8))) short bf16x8;
typedef __attribute__((ext_vector_type(4))) float f32x4;

__device__ __forceinline__ unsigned short f2b(float f) {
    union { float f; unsigned u; } c; c.f = f;
    unsigned r = (c.u + 0x7FFFu + ((c.u >> 16) & 1u)) >> 16;   // RNE
    return (unsigned short)r;
}
__device__ __forceinline__ float blo(unsigned u) { return __uint_as_float(u << 16); }
__device__ __forceinline__ float bhi(unsigned u) { return __uint_as_float(u & 0xffff0000u); }

// ================= prep: W1 -> bf16 transposed + zero overflow counter =============
__global__ __launch_bounds__(256) void k_prep(const float* __restrict__ W1,
                                              unsigned short* __restrict__ w1t,
                                              int* __restrict__ ovf_cnt) {
    int t = blockIdx.x * 256 + threadIdx.x;          // 8192 threads
    if (t == 0) ovf_cnt[0] = 0;
    int k = t >> 6, f = t & 63;                      // W1 is [128][64]
    w1t[f * D_IN + k] = f2b(W1[t]);
}

// ================= one-pass partition, bucket-major fixed-slot regions ==============
// code = (src << 8) | (dst & 255); region pairs[bucket][block][SLOT]
__global__ __launch_bounds__(EST) void k_escatter(const int* __restrict__ src,
                                                  const int* __restrict__ dst,
                                                  int* __restrict__ pairs,
                                                  int* __restrict__ cnt_blk,
                                                  int* __restrict__ ovf_cnt,
                                                  int2* __restrict__ ovf, int E) {
    __shared__ int lcur[NB];
    int tid = threadIdx.x;
    for (int t = tid; t < NB; t += EST) lcur[t] = 0;
    __syncthreads();
    int chunk = (E + NBLK - 1) / NBLK;
    int beg = blockIdx.x * chunk;
    int end = min(beg + chunk, E);
    for (int e = beg + tid; e < end; e += EST) {
        int d = dst[e], s = src[e];
        int bk = d >> BKT_SHIFT;
        int slot = atomicAdd(&lcur[bk], 1);
        if (slot < SLOT)
            pairs[(bk * NBLK + blockIdx.x) * SLOT + slot] = (s << BKT_SHIFT) | (d & (BKT_NODES - 1));
        else {
            int o = atomicAdd(ovf_cnt, 1);
            if (o < OVF_CAP) ovf[o] = make_int2(s, d);
        }
    }
    __syncthreads();
    for (int t = tid; t < NB; t += EST)
        cnt_blk[t * NBLK + blockIdx.x] = min(lcur[t], SLOT);
}

// ===== per-bucket sort: single global read, LDS-staged region, 2 LDS passes ========
__global__ __launch_bounds__(BST) void k_bsort(const uint4* __restrict__ pairs4,
                                               const int* __restrict__ cnt_blk,
                                               const int* __restrict__ ovf_cnt,
                                               const int2* __restrict__ ovf,
                                               int* __restrict__ srcs_sorted,
                                               int* __restrict__ row_start,
                                               int* __restrict__ row_end,
                                               float* __restrict__ dis, int n) {
    __shared__ uint4 reg4[REG4];      // 50,176 B staged region
    __shared__ int segc[NBLK];
    __shared__ int cnt[BKT_NODES];
    __shared__ int exc[BKT_NODES];
    __shared__ int sorted[BKT_CAP];   // 20,480 B
    __shared__ int nE_sh;
    int b = blockIdx.x;
    int tid = threadIdx.x;
    int node0 = b << BKT_SHIFT;
    int ocnt = min(ovf_cnt[0], OVF_CAP);
    const uint4* region = pairs4 + (size_t)b * REG4;

    // stage region -> LDS (coalesced, the ONLY global read of pairs)
    for (int i = tid; i < REG4; i += BST) reg4[i] = region[i];
    for (int i = tid; i < NBLK; i += BST) segc[i] = cnt_blk[b * NBLK + i];
    if (tid < BKT_NODES) cnt[tid] = 0;
    __syncthreads();

    // pass 1: histogram (LDS reads)
    for (int i4 = tid; i4 < REG4; i4 += BST) {
        uint4 v = reg4[i4];
        int c = segc[i4 >> 3];
        int k = (i4 & 7) * 4;
        if (k < c)     atomicAdd(&cnt[v.x & (BKT_NODES - 1)], 1);
        if (k + 1 < c) atomicAdd(&cnt[v.y & (BKT_NODES - 1)], 1);
        if (k + 2 < c) atomicAdd(&cnt[v.z & (BKT_NODES - 1)], 1);
        if (k + 3 < c) atomicAdd(&cnt[v.w & (BKT_NODES - 1)], 1);
    }
    for (int k = tid; k < ocnt; k += BST) {
        int2 e = ovf[k];
        if ((e.y >> BKT_SHIFT) == b) atomicAdd(&cnt[e.y & (BKT_NODES - 1)], 1);
    }
    __syncthreads();

    if (tid < 64) {   // wave-0 exclusive scan of cnt[256]
        int run = 0;
        for (int c = 0; c < BKT_NODES; c += 64) {
            int v = cnt[c + tid];
            int inc = v;
            for (int off = 1; off < 64; off <<= 1) {
                int t2 = __shfl_up(inc, off);
                if (tid >= off) inc += t2;
            }
            exc[c + tid] = run + inc - v;
            run += __shfl(inc, 63);
        }
        if (tid == 63) nE_sh = run;
    }
    __syncthreads();

    if (tid < BKT_NODES) {
        int node = node0 + tid;
        if (node < n) {
            int rs = b * BKT_CAP + exc[tid];
            row_start[node] = rs;
            row_end[node] = rs + cnt[tid];
            dis[node] = rsqrtf((float)cnt[tid] + 1.0f);
        }
    }
    int nE = nE_sh;
    __syncthreads();
    if (tid < BKT_NODES) cnt[tid] = exc[tid];   // repurpose as per-node cursor
    __syncthreads();

    // pass 2: place (LDS reads)
    for (int i4 = tid; i4 < REG4; i4 += BST) {
        uint4 v = reg4[i4];
        int c = segc[i4 >> 3];
        int k = (i4 & 7) * 4;
        if (k < c)     { int p = atomicAdd(&cnt[v.x & (BKT_NODES - 1)], 1); sorted[p] = v.x >> BKT_SHIFT; }
        if (k + 1 < c) { int p = atomicAdd(&cnt[v.y & (BKT_NODES - 1)], 1); sorted[p] = v.y >> BKT_SHIFT; }
        if (k + 2 < c) { int p = atomicAdd(&cnt[v.z & (BKT_NODES - 1)], 1); sorted[p] = v.z >> BKT_SHIFT; }
        if (k + 3 < c) { int p = atomicAdd(&cnt[v.w & (BKT_NODES - 1)], 1); sorted[p] = v.w >> BKT_SHIFT; }
    }
    for (int k = tid; k < ocnt; k += BST) {
        int2 e = ovf[k];
        if ((e.y >> BKT_SHIFT) == b) {
            int p = atomicAdd(&cnt[e.y & (BKT_NODES - 1)], 1);
            sorted[p] = e.x;
        }
    }
    __syncthreads();

    // coalesced write-out
    int gbase = b * BKT_CAP;
    for (int k = tid; k < nE; k += BST)
        srcs_sorted[gbase + k] = sorted[k];
}

// ================= layer 1 GEMM via bf16 MFMA, epilogue pre-scales by dis ===========
#define LS 136
__global__ __launch_bounds__(256) void k_gemm1(const float* __restrict__ x,
                                               const uint4* __restrict__ w1t4,
                                               const float* __restrict__ dis,
                                               unsigned short* __restrict__ h1s, int n) {
    __shared__ unsigned short xs[64 * LS];
    __shared__ unsigned short ws[64 * LS];
    int tid = threadIdx.x;
    int node0 = blockIdx.x * 64;

#pragma unroll
    for (int it = 0; it < 4; ++it) {
        int e = tid + it * 256;
        int f = e >> 4, c = e & 15;
        *(uint4*)&ws[f * LS + c * 8] = w1t4[e];
    }
#pragma unroll
    for (int it = 0; it < 8; ++it) {
        int e4 = tid + it * 256;
        int node = e4 >> 5;
        int k = (e4 & 31) * 4;
        float4 v = make_float4(0.f, 0.f, 0.f, 0.f);
        if (node0 + node < n)
            v = ((const float4*)x)[((size_t)(node0 + node) * D_IN + k) >> 2];
        uint2 u;
        u.x = (unsigned)f2b(v.x) | ((unsigned)f2b(v.y) << 16);
        u.y = (unsigned)f2b(v.z) | ((unsigned)f2b(v.w) << 16);
        *(uint2*)&xs[node * LS + k] = u;
    }
    __syncthreads();

    int wv = tid >> 6;
    int lane = tid & 63;
    int m16 = lane & 15;
    int q = lane >> 4;

    bf16x8 afrag[4];
#pragma unroll
    for (int ks = 0; ks < 4; ++ks)
        afrag[ks] = *(const bf16x8*)&xs[(wv * 16 + m16) * LS + ks * 32 + q * 8];

    f32x4 acc[4];
#pragma unroll
    for (int ft = 0; ft < 4; ++ft) acc[ft] = (f32x4){0.f, 0.f, 0.f, 0.f};

#pragma unroll
    for (int ft = 0; ft < 4; ++ft)
#pragma unroll
        for (int ks = 0; ks < 4; ++ks) {
            bf16x8 bfrag = *(const bf16x8*)&ws[(ft * 16 + m16) * LS + ks * 32 + q * 8];
            acc[ft] = __builtin_amdgcn_mfma_f32_16x16x32_bf16(afrag[ks], bfrag, acc[ft], 0, 0, 0);
        }

#pragma unroll
    for (int r = 0; r < 4; ++r) {
        int node = node0 + wv * 16 + q * 4 + r;
        if (node < n) {
            float d = dis[node];
#pragma unroll
            for (int ft = 0; ft < 4; ++ft)
                h1s[(size_t)node * D_HID + ft * 16 + m16] = f2b(acc[ft][r] * d);
        }
    }
}

// ================= fused agg1 + bias + ReLU + dot(W2) -> zd = z*dis =================
// Round-0 body (measured 47.0us): half-wave per node, 4 edge groups x 8 feat lanes,
// 2-deep unrolled dependent loop. 12500 blocks -> high chip-wide MLP.
__global__ __launch_bounds__(256) void k_gather1(const int* __restrict__ srcs,
                                                 const int* __restrict__ row_start,
                                                 const int* __restrict__ row_end,
                                                 const float* __restrict__ dis,
                                                 const uint4* __restrict__ h4,
                                                 const float* __restrict__ b1,
                                                 const float* __restrict__ W2,
                                                 float* __restrict__ zd, int n) {
    int i = blockIdx.x * 8 + (threadIdx.x >> 5);     // node for this half-wave
    int lane = threadIdx.x & 63;
    int g = (lane >> 3) & 3;  // edge group within half-wave
    int m8 = lane & 7;        // feature block (feats 8*m8 .. 8*m8+7)
    float dd = dis[i];

    float a0, a1, a2, a3, a4, a5, a6, a7;
    {   // self-loop handled by group 0
        uint4 u = h4[(unsigned)i * 8u + m8];
        float w = (g == 0) ? 1.f : 0.f;
        a0 = w * blo(u.x); a1 = w * bhi(u.x);
        a2 = w * blo(u.y); a3 = w * bhi(u.y);
        a4 = w * blo(u.z); a5 = w * bhi(u.z);
        a6 = w * blo(u.w); a7 = w * bhi(u.w);
    }

#define ACC(u) { a0 += blo(u.x); a1 += bhi(u.x); a2 += blo(u.y); a3 += bhi(u.y); \
                 a4 += blo(u.z); a5 += bhi(u.z); a6 += blo(u.w); a7 += bhi(u.w); }
    int end = row_end[i];
    int j = row_start[i] + g;
    for (; j + 4 < end; j += 8) {               // unroll x2: two loads in flight
        int s0 = srcs[j];
        int s1 = srcs[j + 4];
        uint4 u0 = h4[(unsigned)s0 * 8u + m8];
        uint4 u1 = h4[(unsigned)s1 * 8u + m8];
        ACC(u0); ACC(u1);
    }
    if (j < end) {
        int s0 = srcs[j];
        uint4 u0 = h4[(unsigned)s0 * 8u + m8];
        ACC(u0);
    }
#undef ACC

#pragma unroll
    for (int off = 8; off < 32; off <<= 1) {
        a0 += __shfl_xor(a0, off); a1 += __shfl_xor(a1, off);
        a2 += __shfl_xor(a2, off); a3 += __shfl_xor(a3, off);
        a4 += __shfl_xor(a4, off); a5 += __shfl_xor(a5, off);
        a6 += __shfl_xor(a6, off); a7 += __shfl_xor(a7, off);
    }
    float4 ba = ((const float4*)b1)[m8 * 2];
    float4 bb = ((const float4*)b1)[m8 * 2 + 1];
    float4 wa = ((const float4*)W2)[m8 * 2];
    float4 wb = ((const float4*)W2)[m8 * 2 + 1];
    float v = fmaxf(fmaf(dd, a0, ba.x), 0.f) * wa.x + fmaxf(fmaf(dd, a1, ba.y), 0.f) * wa.y
            + fmaxf(fmaf(dd, a2, ba.z), 0.f) * wa.z + fmaxf(fmaf(dd, a3, ba.w), 0.f) * wa.w
            + fmaxf(fmaf(dd, a4, bb.x), 0.f) * wb.x + fmaxf(fmaf(dd, a5, bb.y), 0.f) * wb.y
            + fmaxf(fmaf(dd, a6, bb.z), 0.f) * wb.z + fmaxf(fmaf(dd, a7, bb.w), 0.f) * wb.w;
#pragma unroll
    for (int off = 1; off < 8; off <<= 1) v += __shfl_xor(v, off);
    if ((lane & 31) == 0) zd[i] = v * dd;
}

// ================= agg2 (2 nodes/wave) + fused padded output =================
__global__ __launch_bounds__(256) void k_gather2(const int* __restrict__ srcs,
                                                 const int* __restrict__ row_start,
                                                 const int* __restrict__ row_end,
                                                 const float* __restrict__ dis,
                                                 const float* __restrict__ zd,
                                                 const float* __restrict__ b2,
                                                 float* __restrict__ out, int n) {
    int i = blockIdx.x * 8 + (threadIdx.x >> 5);
    int l = threadIdx.x & 31;
    float acc = 0.f;
    int beg = row_start[i], end = row_end[i];
    for (int j = beg + l; j < end; j += 32)
        acc += zd[srcs[j]];
#pragma unroll
    for (int off = 1; off < 32; off <<= 1) acc += __shfl_xor(acc, off);
    float y = (acc + zd[i]) * dis[i] + b2[0];
    float4 v = make_float4(0.f, 0.f, 0.f, 0.f);
    if (l == 0) v.x = y;
    ((float4*)out)[(size_t)i * 32 + l] = v;
}

extern "C" void kernel_launch(void* const* d_in, const int* in_sizes, int n_in,
                              void* d_out, int out_size, void* d_ws, size_t ws_size,
                              hipStream_t stream) {
    const float* x  = (const float*)d_in[0];
    const int*   ei = (const int*)d_in[1];   // [2, E] int32
    const float* W1 = (const float*)d_in[2];
    const float* b1 = (const float*)d_in[3];
    const float* W2 = (const float*)d_in[4];
    const float* b2 = (const float*)d_in[5];
    float* out = (float*)d_out;

    const int n = N_NODES;
    const int E = N_EDGES;
    const int* src = ei;
    const int* dst = ei + E;

    // ws: pairs int[NB*NBLK*SLOT] (19.6MB) | cnt_blk int[NB*NBLK] (613KB) |
    //     srcs_sorted int[NB*BKT_CAP] (8MB) | row_start[n] | row_end[n] |
    //     ovf_cnt[4] | ovf int2[OVF_CAP] | dis f[n] | h1s ushort[n*64] (12.8MB) |
    //     w1t ushort[8192] | zd f[n]
    int* pairs       = (int*)d_ws;
    int* cnt_blk     = pairs + (size_t)NB * NBLK * SLOT;
    int* srcs_sorted = cnt_blk + (size_t)NB * NBLK;
    int* row_start   = srcs_sorted + (size_t)NB * BKT_CAP;
    int* row_end     = row_start + n;
    int* ovf_cnt     = row_end + n;
    int2* ovf        = (int2*)(ovf_cnt + 4);
    float* dis       = (float*)(ovf + OVF_CAP);
    unsigned short* h1s = (unsigned short*)(dis + n);
    unsigned short* w1t = h1s + (size_t)n * D_HID;
    float* zd        = (float*)(w1t + D_IN * D_HID);

    k_prep<<<32, 256, 0, stream>>>(W1, w1t, ovf_cnt);
    k_escatter<<<NBLK, EST, 0, stream>>>(src, dst, pairs, cnt_blk, ovf_cnt, ovf, E);
    k_bsort<<<NB, BST, 0, stream>>>((const uint4*)pairs, cnt_blk, ovf_cnt, ovf,
                                    srcs_sorted, row_start, row_end, dis, n);

    k_gemm1<<<(n + 63) / 64, 256, 0, stream>>>(x, (const uint4*)w1t, dis, h1s, n);

    k_gather1<<<(n + 7) / 8, 256, 0, stream>>>(srcs_sorted, row_start, row_end, dis,
                                               (const uint4*)h1s, b1, W2, zd, n);
    k_gather2<<<(n + 7) / 8, 256, 0, stream>>>(srcs_sorted, row_start, row_end, dis,
                                               zd, b2, out, n);
}